// Round 16
// baseline (98.690 us; speedup 1.0000x reference)
//
#include <hip/hip_runtime.h>
#include <math.h>

constexpr float WLIM = 5000.0f;
constexpr double RIDGE = 1e-7;

#define G 256             // edge chunks (one block each in k_sort/k_unsort; one thread each in k_node3/k_wsorted)
#define MAXNB 1024        // max buckets (nN up to 131072)
#define BN 128            // nodes per bucket
#define CAP 5120          // LDS edge capacity per bucket in k_node3 (mean 4096, +16 sigma)
#define EBUF_CAP 12544    // LDS edge capacity per chunk in k_sort/k_unsort

// ---------------- Kernel 1: fused per-chunk {histogram, wave-scan, counting sort, dump} ----
// Also writes posmap[e] = within-chunk sorted position (u16) for the final un-permute.
__global__ __launch_bounds__(1024) void k_sort(const int* __restrict__ row,
                                               const int* __restrict__ col,
                                               int* __restrict__ table,
                                               unsigned int* __restrict__ sorted,
                                               unsigned short* __restrict__ posmap,
                                               int nE, int CE, int NB) {
    __shared__ int h[MAXNB];            // histogram -> cursors
    __shared__ int wt[16];
    __shared__ unsigned int ebuf[EBUF_CAP];
    const int g = blockIdx.x, tid = threadIdx.x;
    const int lane = tid & 63, wid = tid >> 6;
    const int s = g * CE;
    const int e_end = min(s + CE, nE);
    const int cnt = e_end - s;
    const bool vec = ((CE & 3) == 0);   // chunk bases 16B-aligned

    for (int i = tid; i < MAXNB; i += 1024) h[i] = 0;
    __syncthreads();
    // pass 1: histogram (LDS int atomics), int4 loads
    if (vec) {
        const int4* r4p = (const int4*)(row + s);
        int nv = cnt >> 2;
        for (int i = tid; i < nv; i += 1024) {
            int4 r4 = r4p[i];
            atomicAdd(&h[r4.x >> 7], 1);
            atomicAdd(&h[r4.y >> 7], 1);
            atomicAdd(&h[r4.z >> 7], 1);
            atomicAdd(&h[r4.w >> 7], 1);
        }
        for (int i = (nv << 2) + tid; i < cnt; i += 1024)
            atomicAdd(&h[row[s + i] >> 7], 1);
    } else {
        for (int i = s + tid; i < e_end; i += 1024)
            atomicAdd(&h[row[i] >> 7], 1);
    }
    __syncthreads();
    // wave-shfl scan of h[0..1023] (2 barriers total)
    int v = h[tid];
    int x = v;
    #pragma unroll
    for (int d = 1; d < 64; d <<= 1) {
        int u = __shfl_up(x, d);
        if (lane >= d) x += u;
    }
    if (lane == 63) wt[wid] = x;
    __syncthreads();
    if (tid < 16) {
        int w = wt[tid];
        int xx = w;
        #pragma unroll
        for (int d = 1; d < 16; d <<= 1) {
            int u = __shfl_up(xx, d);
            if (tid >= d) xx += u;
        }
        wt[tid] = xx - w;               // exclusive wave offset
    }
    __syncthreads();
    int excl = (x - v) + wt[wid];
    if (tid < NB) {
        table[(size_t)tid * G + g] = excl;   // transposed write
        h[tid] = excl;                       // cursor
    }
    if (tid == 0) table[(size_t)NB * G + g] = cnt;
    __syncthreads();
    // pass 2: counting sort into LDS (int4 loads, L2-warm); record positions
    if (vec) {
        const int4* r4p = (const int4*)(row + s);
        const int4* c4p = (const int4*)(col + s);
        ushort4* pm4 = (ushort4*)(posmap + s);
        int nv = cnt >> 2;
        for (int i = tid; i < nv; i += 1024) {
            int4 r4 = r4p[i];
            int4 c4 = c4p[i];
            int p0 = atomicAdd(&h[r4.x >> 7], 1); ebuf[p0] = ((unsigned)(r4.x & 127) << 17) | (unsigned)c4.x;
            int p1 = atomicAdd(&h[r4.y >> 7], 1); ebuf[p1] = ((unsigned)(r4.y & 127) << 17) | (unsigned)c4.y;
            int p2 = atomicAdd(&h[r4.z >> 7], 1); ebuf[p2] = ((unsigned)(r4.z & 127) << 17) | (unsigned)c4.z;
            int p3 = atomicAdd(&h[r4.w >> 7], 1); ebuf[p3] = ((unsigned)(r4.w & 127) << 17) | (unsigned)c4.w;
            pm4[i] = make_ushort4((unsigned short)p0, (unsigned short)p1,
                                  (unsigned short)p2, (unsigned short)p3);
        }
        for (int i = (nv << 2) + tid; i < cnt; i += 1024) {
            int r = row[s + i], c = col[s + i];
            int p = atomicAdd(&h[r >> 7], 1);
            ebuf[p] = ((unsigned)(r & 127) << 17) | (unsigned)c;
            posmap[s + i] = (unsigned short)p;
        }
    } else {
        for (int i = tid; i < cnt; i += 1024) {
            int r = row[s + i], c = col[s + i];
            int p = atomicAdd(&h[r >> 7], 1);
            ebuf[p] = ((unsigned)(r & 127) << 17) | (unsigned)c;
            posmap[s + i] = (unsigned short)p;
        }
    }
    __syncthreads();
    // coalesced dump (uint4)
    if (vec) {
        uint4* dst = (uint4*)(sorted + s);
        const uint4* src = (const uint4*)ebuf;
        int nv = cnt >> 2;
        for (int i = tid; i < nv; i += 1024) dst[i] = src[i];
        for (int i = (nv << 2) + tid; i < cnt; i += 1024) sorted[s + i] = ebuf[i];
    } else {
        for (int i = tid; i < cnt; i += 1024) sorted[s + i] = ebuf[i];
    }
}

// ---------------- Kernel 2: per-bucket two-pass node sort + pair-accumulate + Cholesky ----
// Writes only C (5 floats per node) to rec.
__global__ __launch_bounds__(256) void k_node3(const float2* __restrict__ pos,
                                               const unsigned int* __restrict__ sorted,
                                               const int* __restrict__ table,
                                               float* __restrict__ rec,
                                               int nN, int CE, int NB) {
    __shared__ unsigned int ebuf[CAP];   // node-sorted cols
    __shared__ int cnt[BN];
    __shared__ int off[BN + 1];
    __shared__ int cur[BN];
    __shared__ int goff0[G], glen[G];
    __shared__ int wt2[2];
    const int b = blockIdx.x, tid = threadIdx.x;

    int off0 = table[(size_t)b * G + tid];
    int off1 = table[(size_t)(b + 1) * G + tid];
    int len = off1 - off0;
    goff0[tid] = off0; glen[tid] = len;
    if (tid < BN) cnt[tid] = 0;
    __syncthreads();

    // pass 1: count per local node
    const int gbase = tid * CE + off0;
    for (int j = 0; j < len; ++j)
        atomicAdd(&cnt[sorted[gbase + j] >> 17], 1);
    __syncthreads();
    // 2-wave shfl scan of cnt -> off (exclusive), off[BN] = total
    int sv = 0, sx = 0;
    if (tid < BN) {
        sv = cnt[tid];
        sx = sv;
        #pragma unroll
        for (int d = 1; d < 64; d <<= 1) {
            int u = __shfl_up(sx, d);
            if ((tid & 63) >= d) sx += u;
        }
        if ((tid & 63) == 63) wt2[tid >> 6] = sx;
    }
    __syncthreads();
    if (tid < BN) {
        int incl = sx + ((tid >> 6) ? wt2[0] : 0);
        off[tid] = incl - sv;
        cur[tid] = incl - sv;
        if (tid == BN - 1) off[BN] = incl;
    }
    __syncthreads();
    const int total = off[BN];

    const bool fits = (total <= CAP);
    if (fits) {
        for (int j = 0; j < len; ++j) {
            unsigned v = sorted[gbase + j];
            int p = atomicAdd(&cur[(int)(v >> 17)], 1);
            ebuf[p] = v & 0x1FFFFu;
        }
    }
    __syncthreads();

    // accumulate: 2 threads per node (parity split), shfl_xor combine
    const int node = tid >> 1;
    const int half = tid & 1;
    const int n = (b << 7) + node;
    float m[15];
    #pragma unroll
    for (int i = 0; i < 15; ++i) m[i] = 0.0f;
    float2 pr = make_float2(0.f, 0.f);
    if (n < nN) {
        pr = pos[n];
        if (fits) {
            int j0 = off[node], j1 = off[node + 1];
            for (int j = j0 + half; j < j1; j += 2) {
                float2 pc = pos[ebuf[j]];
                float x = pc.x - pr.x;
                float y = pc.y - pr.y;
                float xy = x * y, xx = x * x, yy = y * y;
                m[0]  += x * x;   m[1]  += x * y;   m[2]  += x * xy;  m[3]  += x * xx;  m[4]  += x * yy;
                m[5]  += y * y;   m[6]  += y * xy;  m[7]  += y * xx;  m[8]  += y * yy;
                m[9]  += xy * xy; m[10] += xy * xx; m[11] += xy * yy;
                m[12] += xx * xx; m[13] += xx * yy;
                m[14] += yy * yy;
            }
        } else {
            for (int g2 = half; g2 < G; g2 += 2) {
                int base2 = g2 * CE + goff0[g2];
                for (int j = 0; j < glen[g2]; ++j) {
                    unsigned v = sorted[base2 + j];
                    if ((int)(v >> 17) == node) {
                        float2 pc = pos[v & 0x1FFFFu];
                        float x = pc.x - pr.x;
                        float y = pc.y - pr.y;
                        float xy = x * y, xx = x * x, yy = y * y;
                        m[0]  += x * x;   m[1]  += x * y;   m[2]  += x * xy;  m[3]  += x * xx;  m[4]  += x * yy;
                        m[5]  += y * y;   m[6]  += y * xy;  m[7]  += y * xx;  m[8]  += y * yy;
                        m[9]  += xy * xy; m[10] += xy * xx; m[11] += xy * yy;
                        m[12] += xx * xx; m[13] += xx * yy;
                        m[14] += yy * yy;
                    }
                }
            }
        }
    }
    #pragma unroll
    for (int i = 0; i < 15; ++i) m[i] += __shfl_xor(m[i], 1);

    if (half == 0 && n < nN) {
        double A[5][5];
        {
            int idx = 0;
            #pragma unroll
            for (int i = 0; i < 5; ++i) {
                #pragma unroll
                for (int j = i; j < 5; ++j) {
                    double vv = (double)m[idx++];
                    A[i][j] = vv;
                    A[j][i] = vv;
                }
            }
        }
        #pragma unroll
        for (int i = 0; i < 5; ++i) A[i][i] += RIDGE;

        #pragma unroll
        for (int k = 0; k < 5; ++k) {
            double d = A[k][k];
            d = sqrt(fmax(d, 1e-300));
            A[k][k] = d;
            double inv = 1.0 / d;
            #pragma unroll
            for (int i = k + 1; i < 5; ++i) A[i][k] *= inv;
            #pragma unroll
            for (int j = k + 1; j < 5; ++j) {
                #pragma unroll
                for (int i = j; i < 5; ++i) A[i][j] -= A[i][k] * A[j][k];
            }
        }
        double bb[5] = {0.0, 0.0, 0.0, 2.0, 2.0};
        double y[5];
        #pragma unroll
        for (int i = 0; i < 5; ++i) {
            double sv2 = bb[i];
            #pragma unroll
            for (int k = 0; k < 5; ++k) {
                if (k < i) sv2 -= A[i][k] * y[k];
            }
            y[i] = sv2 / A[i][i];
        }
        double xs[5];
        #pragma unroll
        for (int ii = 4; ii >= 0; --ii) {
            double sv2 = y[ii];
            #pragma unroll
            for (int k = 0; k < 5; ++k) {
                if (k > ii) sv2 -= A[k][ii] * xs[k];
            }
            xs[ii] = sv2 / A[ii][ii];
        }
        float* cb = rec + (size_t)n * 5;
        #pragma unroll
        for (int i = 0; i < 5; ++i) cb[i] = (float)xs[i];
    }
}

// ---------------- Kernel 3: per-bucket sorted-order weights, in-place overwrite ----------------
// Block b stages its 128 C-vectors + pos_r in LDS (stride 7 -> conflict-free-ish),
// walks its runs, computes w, overwrites sorted with f32 w. 1 divergent gather/edge.
__global__ __launch_bounds__(256) void k_wsorted(const float2* __restrict__ pos,
                                                 unsigned int* __restrict__ sorted,
                                                 const int* __restrict__ table,
                                                 const float* __restrict__ rec,
                                                 int nN, int CE, int NB) {
    __shared__ float crec[BN * 7];      // C0..C4, pos_r.x, pos_r.y (stride 7: gcd(7,32)=1)
    const int b = blockIdx.x, tid = threadIdx.x;
    // stage C: rec slice [(b<<7)*5, +BN*5) is contiguous (rec padded to NB*BN nodes)
    for (int i = tid; i < BN * 5; i += 256) {
        int node = i / 5, k = i - node * 5;
        crec[node * 7 + k] = rec[(size_t)(b << 7) * 5 + i];
    }
    if (tid < BN) {
        int n = (b << 7) + tid;
        float2 p = (n < nN) ? pos[n] : make_float2(0.f, 0.f);
        crec[tid * 7 + 5] = p.x;
        crec[tid * 7 + 6] = p.y;
    }
    __syncthreads();

    int off0 = table[(size_t)b * G + tid];
    int off1 = table[(size_t)(b + 1) * G + tid];
    int len = off1 - off0;
    const int gbase = tid * CE + off0;
    float* wout = (float*)sorted;
    for (int j = 0; j < len; ++j) {
        unsigned v = sorted[gbase + j];
        int lr = (int)(v >> 17);
        int c = (int)(v & 0x1FFFFu);
        const float* cb = &crec[lr * 7];
        float2 pc = pos[c];
        float x = pc.x - cb[5];
        float y = pc.y - cb[6];
        float w = cb[0] * x + cb[1] * y + cb[2] * (x * y) + cb[3] * (x * x) + cb[4] * (y * y);
        w = fminf(fmaxf(w, -WLIM), WLIM);
        wout[gbase + j] = w;
    }
}

// ---------------- Kernel 4: un-permute — out[e] = w_sorted[posmap[e]] via LDS staging ----
__global__ __launch_bounds__(1024) void k_unsort(const float* __restrict__ wsorted,
                                                 const unsigned short* __restrict__ posmap,
                                                 float* __restrict__ out, int nE, int CE) {
    __shared__ float wl[EBUF_CAP];
    const int g = blockIdx.x, tid = threadIdx.x;
    const int s = g * CE;
    const int e_end = min(s + CE, nE);
    const int cnt = e_end - s;
    const bool vec = ((CE & 3) == 0);
    if (vec) {
        const uint4* src = (const uint4*)(wsorted + s);
        uint4* dstl = (uint4*)wl;
        int nv = cnt >> 2;
        for (int i = tid; i < nv; i += 1024) dstl[i] = src[i];
        for (int i = (nv << 2) + tid; i < cnt; i += 1024) wl[i] = wsorted[s + i];
        __syncthreads();
        const ushort4* pm4 = (const ushort4*)(posmap + s);
        float4* out4 = (float4*)(out + s);
        for (int i = tid; i < nv; i += 1024) {
            ushort4 p4 = pm4[i];
            float4 o;
            o.x = wl[p4.x]; o.y = wl[p4.y]; o.z = wl[p4.z]; o.w = wl[p4.w];
            out4[i] = o;
        }
        for (int i = (nv << 2) + tid; i < cnt; i += 1024) out[s + i] = wl[posmap[s + i]];
    } else {
        for (int i = tid; i < cnt; i += 1024) wl[i] = wsorted[s + i];
        __syncthreads();
        for (int i = tid; i < cnt; i += 1024) out[s + i] = wl[posmap[s + i]];
    }
}

extern "C" void kernel_launch(void* const* d_in, const int* in_sizes, int n_in,
                              void* d_out, int out_size, void* d_ws, size_t ws_size,
                              hipStream_t stream) {
    const float2* pos = (const float2*)d_in[0];
    const int* ei = (const int*)d_in[1];
    const int nN = in_sizes[0] / 2;   // (N,2) f32
    const int nE = in_sizes[1] / 2;   // (2,E) int32
    const int* row = ei;
    const int* col = ei + nE;

    const int NB = (nN + BN - 1) >> 7;        // buckets of 128 nodes (782)
    const int CE = (nE + G - 1) / G;          // edges per chunk (12500 <= EBUF_CAP, < 16384 for u16)

    // ws layout: table[(NB+1)*G] ints | rec[NB*BN*5] floats (padded) | align 8B | posmap u16
    // total ~= 0.8 + 2.0 + 6.4 = 9.2MB (<= 9.6MB proven in R1)
    int* table = (int*)d_ws;
    float* rec = (float*)(table + (size_t)(NB + 1) * G);
    size_t pm_off_ints = ((size_t)(NB + 1) * G + (size_t)NB * BN * 5 + 1) & ~(size_t)1;
    unsigned short* posmap = (unsigned short*)((int*)d_ws + pm_off_ints);

    unsigned int* sorted = (unsigned int*)d_out;  // packed edges -> overwritten with weights -> out
    float* out = (float*)d_out;

    k_sort<<<G, 1024, 0, stream>>>(row, col, table, sorted, posmap, nE, CE, NB);
    k_node3<<<NB, 256, 0, stream>>>(pos, sorted, table, rec, nN, CE, NB);
    k_wsorted<<<NB, 256, 0, stream>>>(pos, sorted, table, rec, nN, CE, NB);
    k_unsort<<<G, 1024, 0, stream>>>((const float*)sorted, posmap, out, nE, CE);
}

// Round 17
// 85.121 us; speedup vs baseline: 1.1594x; 1.1594x over previous
//
#include <hip/hip_runtime.h>
#include <math.h>

constexpr float WLIM = 5000.0f;
constexpr double RIDGE = 1e-7;

#define G 256             // edge chunks (one block each in k_sort; one thread each in k_node3)
#define MAXNB 1024        // max buckets (nN up to 131072)
#define BN 128            // nodes per bucket
#define CAP 5120          // LDS edge capacity per bucket in k_node3 (mean 4096, +16 sigma)
#define EBUF_CAP 12544    // LDS edge capacity per chunk in k_sort

// ---------------- Kernel 1: fused per-chunk {histogram, wave-scan, counting sort, dump} ----
// R13 lesson: G=256 keeps per-(chunk,bucket) runs at ~16 edges (~64B); halving chunk
// size quadruples line overfetch in k_node3 (FETCH 25->120MB). Do not raise G.
__global__ __launch_bounds__(1024) void k_sort(const int* __restrict__ row,
                                               const int* __restrict__ col,
                                               int* __restrict__ table,
                                               unsigned int* __restrict__ sorted,
                                               int nE, int CE, int NB) {
    __shared__ int h[MAXNB];            // histogram -> cursors
    __shared__ int wt[16];
    __shared__ unsigned int ebuf[EBUF_CAP];
    const int g = blockIdx.x, tid = threadIdx.x;
    const int lane = tid & 63, wid = tid >> 6;
    const int s = g * CE;
    const int e_end = min(s + CE, nE);
    const int cnt = e_end - s;
    const bool vec = ((CE & 3) == 0);   // chunk bases 16B-aligned

    for (int i = tid; i < MAXNB; i += 1024) h[i] = 0;
    __syncthreads();
    // pass 1: histogram (LDS int atomics), int4 loads
    if (vec) {
        const int4* r4p = (const int4*)(row + s);
        int nv = cnt >> 2;
        for (int i = tid; i < nv; i += 1024) {
            int4 r4 = r4p[i];
            atomicAdd(&h[r4.x >> 7], 1);
            atomicAdd(&h[r4.y >> 7], 1);
            atomicAdd(&h[r4.z >> 7], 1);
            atomicAdd(&h[r4.w >> 7], 1);
        }
        for (int i = (nv << 2) + tid; i < cnt; i += 1024)
            atomicAdd(&h[row[s + i] >> 7], 1);
    } else {
        for (int i = s + tid; i < e_end; i += 1024)
            atomicAdd(&h[row[i] >> 7], 1);
    }
    __syncthreads();
    // wave-shfl scan of h[0..1023] (2 barriers total)
    int v = h[tid];
    int x = v;
    #pragma unroll
    for (int d = 1; d < 64; d <<= 1) {
        int u = __shfl_up(x, d);
        if (lane >= d) x += u;
    }
    if (lane == 63) wt[wid] = x;
    __syncthreads();
    if (tid < 16) {
        int w = wt[tid];
        int xx = w;
        #pragma unroll
        for (int d = 1; d < 16; d <<= 1) {
            int u = __shfl_up(xx, d);
            if (tid >= d) xx += u;
        }
        wt[tid] = xx - w;               // exclusive wave offset
    }
    __syncthreads();
    int excl = (x - v) + wt[wid];
    if (tid < NB) {
        table[(size_t)tid * G + g] = excl;   // transposed write
        h[tid] = excl;                       // cursor
    }
    if (tid == 0) table[(size_t)NB * G + g] = cnt;
    __syncthreads();
    // pass 2: counting sort into LDS (int4 loads, L2-warm)
    if (vec) {
        const int4* r4p = (const int4*)(row + s);
        const int4* c4p = (const int4*)(col + s);
        int nv = cnt >> 2;
        for (int i = tid; i < nv; i += 1024) {
            int4 r4 = r4p[i];
            int4 c4 = c4p[i];
            int p;
            p = atomicAdd(&h[r4.x >> 7], 1); ebuf[p] = ((unsigned)(r4.x & 127) << 17) | (unsigned)c4.x;
            p = atomicAdd(&h[r4.y >> 7], 1); ebuf[p] = ((unsigned)(r4.y & 127) << 17) | (unsigned)c4.y;
            p = atomicAdd(&h[r4.z >> 7], 1); ebuf[p] = ((unsigned)(r4.z & 127) << 17) | (unsigned)c4.z;
            p = atomicAdd(&h[r4.w >> 7], 1); ebuf[p] = ((unsigned)(r4.w & 127) << 17) | (unsigned)c4.w;
        }
        for (int i = (nv << 2) + tid; i < cnt; i += 1024) {
            int r = row[s + i], c = col[s + i];
            int p = atomicAdd(&h[r >> 7], 1);
            ebuf[p] = ((unsigned)(r & 127) << 17) | (unsigned)c;
        }
    } else {
        for (int i = s + tid; i < e_end; i += 1024) {
            int r = row[i], c = col[i];
            int p = atomicAdd(&h[r >> 7], 1);
            ebuf[p] = ((unsigned)(r & 127) << 17) | (unsigned)c;
        }
    }
    __syncthreads();
    // coalesced dump (uint4)
    if (vec) {
        uint4* dst = (uint4*)(sorted + s);
        const uint4* src = (const uint4*)ebuf;
        int nv = cnt >> 2;
        for (int i = tid; i < nv; i += 1024) dst[i] = src[i];
        for (int i = (nv << 2) + tid; i < cnt; i += 1024) sorted[s + i] = ebuf[i];
    } else {
        for (int i = tid; i < cnt; i += 1024) sorted[s + i] = ebuf[i];
    }
}

// ---------------- Kernel 2: per-bucket two-pass node sort + pair-accumulate + Cholesky ----
__global__ __launch_bounds__(256) void k_node3(const float2* __restrict__ pos,
                                               const unsigned int* __restrict__ sorted,
                                               const int* __restrict__ table,
                                               float* __restrict__ rec,
                                               int nN, int CE, int NB) {
    __shared__ unsigned int ebuf[CAP];   // node-sorted cols
    __shared__ int cnt[BN];
    __shared__ int off[BN + 1];
    __shared__ int cur[BN];
    __shared__ int goff0[G], glen[G];
    __shared__ int wt2[2];
    const int b = blockIdx.x, tid = threadIdx.x;

    int off0 = table[(size_t)b * G + tid];
    int off1 = table[(size_t)(b + 1) * G + tid];
    int len = off1 - off0;
    goff0[tid] = off0; glen[tid] = len;
    if (tid < BN) cnt[tid] = 0;
    __syncthreads();

    // pass 1: count per local node
    const int gbase = tid * CE + off0;
    for (int j = 0; j < len; ++j)
        atomicAdd(&cnt[sorted[gbase + j] >> 17], 1);
    __syncthreads();
    // 2-wave shfl scan of cnt -> off (exclusive), off[BN] = total
    int sv = 0, sx = 0;
    if (tid < BN) {
        sv = cnt[tid];
        sx = sv;
        #pragma unroll
        for (int d = 1; d < 64; d <<= 1) {
            int u = __shfl_up(sx, d);
            if ((tid & 63) >= d) sx += u;
        }
        if ((tid & 63) == 63) wt2[tid >> 6] = sx;
    }
    __syncthreads();
    if (tid < BN) {
        int incl = sx + ((tid >> 6) ? wt2[0] : 0);
        off[tid] = incl - sv;
        cur[tid] = incl - sv;
        if (tid == BN - 1) off[BN] = incl;
    }
    __syncthreads();
    const int total = off[BN];

    const bool fits = (total <= CAP);
    if (fits) {
        // pass 2: re-read runs (L2-warm), place col at final node-sorted slot
        for (int j = 0; j < len; ++j) {
            unsigned v = sorted[gbase + j];
            int p = atomicAdd(&cur[(int)(v >> 17)], 1);
            ebuf[p] = v & 0x1FFFFu;
        }
    }
    __syncthreads();

    // accumulate: 2 threads per node (parity split), shfl_xor combine
    const int node = tid >> 1;
    const int half = tid & 1;
    const int n = (b << 7) + node;
    float m[15];
    #pragma unroll
    for (int i = 0; i < 15; ++i) m[i] = 0.0f;
    float2 pr = make_float2(0.f, 0.f);
    if (n < nN) {
        pr = pos[n];
        if (fits) {
            int j0 = off[node], j1 = off[node + 1];
            for (int j = j0 + half; j < j1; j += 2) {
                float2 pc = pos[ebuf[j]];
                float x = pc.x - pr.x;
                float y = pc.y - pr.y;
                float xy = x * y, xx = x * x, yy = y * y;
                m[0]  += x * x;   m[1]  += x * y;   m[2]  += x * xy;  m[3]  += x * xx;  m[4]  += x * yy;
                m[5]  += y * y;   m[6]  += y * xy;  m[7]  += y * xx;  m[8]  += y * yy;
                m[9]  += xy * xy; m[10] += xy * xx; m[11] += xy * yy;
                m[12] += xx * xx; m[13] += xx * yy;
                m[14] += yy * yy;
            }
        } else {
            // overflow fallback (statistically never): walk all runs, filter by node
            for (int g2 = half; g2 < G; g2 += 2) {
                int base2 = g2 * CE + goff0[g2];
                for (int j = 0; j < glen[g2]; ++j) {
                    unsigned v = sorted[base2 + j];
                    if ((int)(v >> 17) == node) {
                        float2 pc = pos[v & 0x1FFFFu];
                        float x = pc.x - pr.x;
                        float y = pc.y - pr.y;
                        float xy = x * y, xx = x * x, yy = y * y;
                        m[0]  += x * x;   m[1]  += x * y;   m[2]  += x * xy;  m[3]  += x * xx;  m[4]  += x * yy;
                        m[5]  += y * y;   m[6]  += y * xy;  m[7]  += y * xx;  m[8]  += y * yy;
                        m[9]  += xy * xy; m[10] += xy * xx; m[11] += xy * yy;
                        m[12] += xx * xx; m[13] += xx * yy;
                        m[14] += yy * yy;
                    }
                }
            }
        }
    }
    #pragma unroll
    for (int i = 0; i < 15; ++i) m[i] += __shfl_xor(m[i], 1);

    if (half == 0 && n < nN) {
        double A[5][5];
        {
            int idx = 0;
            #pragma unroll
            for (int i = 0; i < 5; ++i) {
                #pragma unroll
                for (int j = i; j < 5; ++j) {
                    double vv = (double)m[idx++];
                    A[i][j] = vv;
                    A[j][i] = vv;
                }
            }
        }
        #pragma unroll
        for (int i = 0; i < 5; ++i) A[i][i] += RIDGE;

        #pragma unroll
        for (int k = 0; k < 5; ++k) {
            double d = A[k][k];
            d = sqrt(fmax(d, 1e-300));
            A[k][k] = d;
            double inv = 1.0 / d;
            #pragma unroll
            for (int i = k + 1; i < 5; ++i) A[i][k] *= inv;
            #pragma unroll
            for (int j = k + 1; j < 5; ++j) {
                #pragma unroll
                for (int i = j; i < 5; ++i) A[i][j] -= A[i][k] * A[j][k];
            }
        }
        double bb[5] = {0.0, 0.0, 0.0, 2.0, 2.0};
        double y[5];
        #pragma unroll
        for (int i = 0; i < 5; ++i) {
            double sv2 = bb[i];
            #pragma unroll
            for (int k = 0; k < 5; ++k) {
                if (k < i) sv2 -= A[i][k] * y[k];
            }
            y[i] = sv2 / A[i][i];
        }
        double xs[5];
        #pragma unroll
        for (int ii = 4; ii >= 0; --ii) {
            double sv2 = y[ii];
            #pragma unroll
            for (int k = 0; k < 5; ++k) {
                if (k > ii) sv2 -= A[k][ii] * xs[k];
            }
            xs[ii] = sv2 / A[ii][ii];
        }
        float4* rb = (float4*)(rec + (size_t)n * 8);
        rb[0] = make_float4((float)xs[0], (float)xs[1], (float)xs[2], (float)xs[3]);
        rb[1] = make_float4((float)xs[4], pr.x, pr.y, 0.0f);
    }
}

// ---------------- Kernel 3: per-edge weight, 1 edge/thread (max TLP), nt streams ----------------
// MSHR/TA-bound at 3 divergent gather instructions per edge (rec 2x16B same line + pos 8B);
// 1 edge/thread maximizes outstanding misses (R11: 4/thread -25%). nt keeps the 38MB
// row/col/out streams from evicting the rec+pos gather set (R12: -25%). Sorted-order
// weight computation refuted twice (R15/R16: 3.6x write amplification exceeds savings).
__global__ __launch_bounds__(256) void k_weights(const float2* __restrict__ pos,
                                                 const int* __restrict__ row,
                                                 const int* __restrict__ col,
                                                 const float* __restrict__ rec,
                                                 float* __restrict__ out,
                                                 int nE) {
    int e = blockIdx.x * blockDim.x + threadIdx.x;
    if (e >= nE) return;
    int r = __builtin_nontemporal_load(row + e);
    int c = __builtin_nontemporal_load(col + e);
    const float4* rb = (const float4*)(rec + (size_t)r * 8);
    float4 q0 = rb[0];               // C0..C3
    float4 q1 = rb[1];               // C4, pos_r.x, pos_r.y, pad
    float2 pc = pos[c];
    float x = pc.x - q1.y;
    float y = pc.y - q1.z;
    float w = q0.x * x + q0.y * y + q0.z * (x * y) + q0.w * (x * x) + q1.x * (y * y);
    w = fminf(fmaxf(w, -WLIM), WLIM);
    __builtin_nontemporal_store(w, out + e);
}

extern "C" void kernel_launch(void* const* d_in, const int* in_sizes, int n_in,
                              void* d_out, int out_size, void* d_ws, size_t ws_size,
                              hipStream_t stream) {
    const float2* pos = (const float2*)d_in[0];
    const int* ei = (const int*)d_in[1];
    const int nN = in_sizes[0] / 2;   // (N,2) f32
    const int nE = in_sizes[1] / 2;   // (2,E) int32
    const int* row = ei;
    const int* col = ei + nE;

    const int NB = (nN + BN - 1) >> 7;        // buckets of 128 nodes (782)
    const int CE = (nE + G - 1) / G;          // edges per chunk (12500 <= EBUF_CAP)

    // ws layout: table[(NB+1)*G] | pad to 16B | rec[nN*8 floats]
    int* table = (int*)d_ws;
    size_t roff = (((size_t)(NB + 1) * G) + 3) & ~(size_t)3;
    float* rec = (float*)((int*)d_ws + roff);

    unsigned int* sorted = (unsigned int*)d_out;  // consumed by k_node3 before k_weights overwrites
    float* out = (float*)d_out;

    k_sort<<<G, 1024, 0, stream>>>(row, col, table, sorted, nE, CE, NB);
    k_node3<<<NB, 256, 0, stream>>>(pos, sorted, table, rec, nN, CE, NB);
    k_weights<<<(nE + 255) / 256, 256, 0, stream>>>(pos, row, col, rec, out, nE);
}